// Round 19
// baseline (437.535 us; speedup 1.0000x reference)
//
#include <hip/hip_runtime.h>
#include <hip/hip_bf16.h>
#include <math.h>

#define N_ROWS 65536
#define ZDIM   256
#define KCODES 1024
#define IDX_OFF  (N_ROWS * ZDIM)        // 16777216
#define LOSS_OFF (IDX_OFF + N_ROWS)     // 16842752
#define ZQ_BLOCKS 2048
#define SLOTS 4
#define NC16 16                          // cqmin granularity: 16 chunks of 64
#define NC8  8                           // cand-list granularity: 8 chunks of 128
#define MAXP 16                          // max pairs per row before scan-mode

typedef unsigned int u32;
typedef unsigned short u16;
typedef unsigned long long u64;
typedef __attribute__((ext_vector_type(8))) _Float16 hfrag;  // 8 fp16 (4 VGPR)
typedef __attribute__((ext_vector_type(4))) float ffrag;     // 4 fp32 acc

__device__ __forceinline__ u16 f2h(float x) {
    union { _Float16 h; u16 u; } c; c.h = (_Float16)x; return c.u;   // RN
}

// monotone float->u32 map (total order preserved, incl. negatives)
__device__ __forceinline__ u32 mono32(float d) {
    u32 b = __float_as_uint(d);
    return (b & 0x80000000u) ? ~b : (b | 0x80000000u);
}

// ---------------- numpy-pairwise helpers (256 cols) ----------------
__device__ __forceinline__ float np_pw128_sq(const float* __restrict__ p) {
    float r[8];
#pragma unroll
    for (int j = 0; j < 8; ++j) r[j] = __fmul_rn(p[j], p[j]);
    for (int i = 8; i < 128; i += 8) {
#pragma unroll
        for (int j = 0; j < 8; ++j)
            r[j] = __fadd_rn(r[j], __fmul_rn(p[i + j], p[i + j]));
    }
    float a = __fadd_rn(__fadd_rn(r[0], r[1]), __fadd_rn(r[2], r[3]));
    float b = __fadd_rn(__fadd_rn(r[4], r[5]), __fadd_rn(r[6], r[7]));
    return __fadd_rn(a, b);
}

__device__ __forceinline__ float pw128_abs(const float* __restrict__ p) {
    float r[8];
#pragma unroll
    for (int j = 0; j < 8; ++j) r[j] = fabsf(p[j]);
    for (int i = 8; i < 128; i += 8) {
#pragma unroll
        for (int j = 0; j < 8; ++j) r[j] += fabsf(p[i + j]);
    }
    return ((r[0] + r[1]) + (r[2] + r[3])) + ((r[4] + r[5]) + (r[6] + r[7]));
}

// exact OpenBLAS-order dot, float4 loads (same fmaf sequence, 4x fewer loads)
__device__ __forceinline__ float exact_dot(const float* __restrict__ zr,
                                           const float* __restrict__ er) {
    float m = 0.0f;
#pragma unroll 4
    for (int k = 0; k < ZDIM; k += 4) {
        float4 a = *(const float4*)(zr + k);
        float4 b = *(const float4*)(er + k);
        m = fmaf(a.x, b.x, m);
        m = fmaf(a.y, b.y, m);
        m = fmaf(a.z, b.z, m);
        m = fmaf(a.w, b.w, m);
    }
    return m;
}

__global__ void rowsq_kernel(const float* __restrict__ x, float* __restrict__ s, int nrows) {
    int r = blockIdx.x * blockDim.x + threadIdx.x;
    if (r >= nrows) return;
    const float* p = x + (size_t)r * ZDIM;
    s[r] = __fadd_rn(np_pw128_sq(p), np_pw128_sq(p + 128));
}

// sz (np-exact) + per-row rigorous eps for the 1-pass fp16 bound
__global__ void rowsq_eps_kernel(const float* __restrict__ x, float* __restrict__ s,
                                 float* __restrict__ epsr) {
    int r = blockIdx.x * blockDim.x + threadIdx.x;
    const float* p = x + (size_t)r * ZDIM;
    s[r] = __fadd_rn(np_pw128_sq(p), np_pw128_sq(p + 128));
    float S1 = pw128_abs(p) + pw128_abs(p + 128);
    epsr[r] = fmaf(S1, 1.1e-6f, 6e-5f);
}

// ---------------- z -> fp16 (RN), row-major, into d_out z_q region ----------
__global__ __launch_bounds__(256) void split_z_kernel(
    const float* __restrict__ z, u16* __restrict__ zh) {
    int t = blockIdx.x * 256 + threadIdx.x;
    int i = t * 8;
    float4 a = *(const float4*)(z + i);
    float4 b = *(const float4*)(z + i + 4);
    uint4 w;
    w.x = ((u32)f2h(a.y) << 16) | f2h(a.x);
    w.y = ((u32)f2h(a.w) << 16) | f2h(a.z);
    w.z = ((u32)f2h(b.y) << 16) | f2h(b.x);
    w.w = ((u32)f2h(b.w) << 16) | f2h(b.z);
    *(uint4*)(zh + i) = w;
}

// ---------------- e -> fp16 scaled x64, FRAGMENT-MAJOR layout ----------------
__global__ __launch_bounds__(256) void split_e_kernel(
    const float* __restrict__ e, u16* __restrict__ ehf) {
    int t = blockIdx.x * 256 + threadIdx.x;      // 65536 threads
    int c = t >> 6, kq = t & 63;                 // dims kq*4 .. +3
    float4 v = *(const float4*)(e + (size_t)c * ZDIM + kq * 4);
    ushort4 h;
    h.x = f2h(v.x * 64.0f); h.y = f2h(v.y * 64.0f);
    h.z = f2h(v.z * 64.0f); h.w = f2h(v.w * 64.0f);
    int c16 = c >> 6, ct = (c >> 4) & 3, lr = c & 15;
    int kc = kq >> 3, lk = (kq >> 1) & 3;
    int lane = lk * 16 + lr;
    size_t base = ((size_t)((c16 * 8 + kc) * 4 + ct) * 64 + lane) * 8 + ((kq * 4) & 7);
    *(ushort4*)(ehf + base) = h;
}

// ---------------- LDS-shared 1-pass fp16 MFMA (reg-staged) ------------------
// v19: B fragments staged per 16KB segment into double-buffered LDS via
// NORMAL loads (global -> VGPR -> ds_write) so the L2-cached path is kept
// (r18's global_load_lds DMA bypassed L2: FETCH 35->294 MB). All 4 waves
// share staged B: L2 line-requests /4 vs r17. One barrier per segment;
// loads for seg+1 issued before compute(seg) (T14). Bit-identical math.
__global__ __launch_bounds__(256) void mfma_argmin_kernel(
    const u16* __restrict__ zh, const u16* __restrict__ ehf,
    const float* __restrict__ sz, const float* __restrict__ se,
    const float* __restrict__ epsr, float* __restrict__ cqmin,
    int* __restrict__ cnt, float* __restrict__ cand_d, int* __restrict__ cand_i) {
    __shared__ __align__(16) char ehL[2][16384];      // 32 KB (double buffer)
    __shared__ float sse[KCODES];                     // 4 KB
    const int tid = threadIdx.x;
    const int w = tid >> 6, lane = tid & 63;
    const int lr = lane & 15, lk = lane >> 4;
    const int rp = blockIdx.x >> 1, cp = blockIdx.x & 1;
    const int wr0 = rp * 128 + w * 32;

    *(float4*)(sse + tid * 4) = *(const float4*)(se + tid * 4);

    float szv[2][4], epsv[2][4];
#pragma unroll
    for (int rt = 0; rt < 2; ++rt)
#pragma unroll
        for (int j = 0; j < 4; ++j) {
            szv[rt][j]  = sz[wr0 + rt * 16 + lk * 4 + j];
            epsv[rt][j] = epsr[wr0 + rt * 16 + lk * 4 + j];
        }

    hfrag A[2][8];
#pragma unroll
    for (int rt = 0; rt < 2; ++rt)
#pragma unroll
        for (int kc = 0; kc < 8; ++kc)
            A[rt][kc] = *(const hfrag*)(zh + (size_t)(wr0 + rt * 16 + lr) * ZDIM + kc * 32 + lk * 8);

    const char* ehpb = (const char*)ehf + (size_t)cp * 8 * 32768;  // this cp half

    // prologue: stage segment 0 (each thread: 4 coalesced b128 -> ds_write)
    {
        const char* src = ehpb;
        uint4 st0 = *(const uint4*)(src + tid * 16);
        uint4 st1 = *(const uint4*)(src + 4096 + tid * 16);
        uint4 st2 = *(const uint4*)(src + 8192 + tid * 16);
        uint4 st3 = *(const uint4*)(src + 12288 + tid * 16);
        *(uint4*)(&ehL[0][tid * 16])         = st0;
        *(uint4*)(&ehL[0][4096 + tid * 16])  = st1;
        *(uint4*)(&ehL[0][8192 + tid * 16])  = st2;
        *(uint4*)(&ehL[0][12288 + tid * 16]) = st3;
    }
    __syncthreads();   // seg0 staged; also covers sse init

    ffrag acc[2][4];

#pragma unroll 1
    for (int seg = 0; seg < 16; ++seg) {
        const int cc = seg >> 1;        // chunk index within cp half
        const int h  = seg & 1;         // half: kc 0-3 or 4-7
        const int c16 = cp * 8 + cc;
        const int c8  = c16 >> 1;

        if (h == 0) {
#pragma unroll
            for (int rt = 0; rt < 2; ++rt)
#pragma unroll
                for (int ct = 0; ct < 4; ++ct) acc[rt][ct] = (ffrag)(0.0f);
        }
        // issue loads for seg+1 into regs (latency hides under compute)
        uint4 st0, st1, st2, st3;
        if (seg < 15) {
            const char* src = ehpb + (size_t)(seg + 1) * 16384;
            st0 = *(const uint4*)(src + tid * 16);
            st1 = *(const uint4*)(src + 4096 + tid * 16);
            st2 = *(const uint4*)(src + 8192 + tid * 16);
            st3 = *(const uint4*)(src + 12288 + tid * 16);
        }
        // compute this segment from LDS (contiguous b128 reads, conflict-free)
        const char* buf = ehL[seg & 1];
#pragma unroll
        for (int kcl = 0; kcl < 4; ++kcl) {
            const int kc = h * 4 + kcl;
#pragma unroll
            for (int ct = 0; ct < 4; ++ct) {
                hfrag bh = *(const hfrag*)(buf + (size_t)(kcl * 4 + ct) * 1024 + (size_t)lane * 16);
                acc[0][ct] = __builtin_amdgcn_mfma_f32_16x16x32_f16(A[0][kc], bh, acc[0][ct], 0, 0, 0);
                acc[1][ct] = __builtin_amdgcn_mfma_f32_16x16x32_f16(A[1][kc], bh, acc[1][ct], 0, 0, 0);
            }
        }
        // write staged regs into the other buffer (read during seg+1)
        if (seg < 15) {
            char* dst = ehL[(seg + 1) & 1];
            *(uint4*)(dst + tid * 16)         = st0;
            *(uint4*)(dst + 4096 + tid * 16)  = st1;
            *(uint4*)(dst + 8192 + tid * 16)  = st2;
            *(uint4*)(dst + 12288 + tid * 16) = st3;
        }

        if (h == 1) {
            // ---- epilogue for c16: d~ = fl(fl(sz+se) - acc/32) ----
            float rmin[2][4];
#pragma unroll
            for (int rt = 0; rt < 2; ++rt)
#pragma unroll
                for (int j = 0; j < 4; ++j) rmin[rt][j] = __builtin_inff();
#pragma unroll
            for (int rt = 0; rt < 2; ++rt)
#pragma unroll
                for (int ct = 0; ct < 4; ++ct) {
                    float sec = sse[c16 * 64 + ct * 16 + lr];
#pragma unroll
                    for (int j = 0; j < 4; ++j) {
                        float dd = __fsub_rn(__fadd_rn(szv[rt][j], sec), 0.03125f * acc[rt][ct][j]);
                        rmin[rt][j] = fminf(rmin[rt][j], dd);
                    }
                }
#pragma unroll
            for (int m = 1; m < 16; m <<= 1)
#pragma unroll
                for (int rt = 0; rt < 2; ++rt)
#pragma unroll
                    for (int j = 0; j < 4; ++j)
                        rmin[rt][j] = fminf(rmin[rt][j], __shfl_xor(rmin[rt][j], m, 64));
            if (lr == 0) {
#pragma unroll
                for (int rt = 0; rt < 2; ++rt)
#pragma unroll
                    for (int j = 0; j < 4; ++j)
                        cqmin[(size_t)(wr0 + rt * 16 + lk * 4 + j) * NC16 + c16] = rmin[rt][j];
            }
#pragma unroll
            for (int rt = 0; rt < 2; ++rt)
#pragma unroll
                for (int j = 0; j < 4; ++j) {
                    const float thr = fmaf(2.0f, epsv[rt][j], rmin[rt][j]);
                    const int grow = wr0 + rt * 16 + lk * 4 + j;
#pragma unroll
                    for (int ct = 0; ct < 4; ++ct) {
                        float dd = __fsub_rn(__fadd_rn(szv[rt][j], sse[c16 * 64 + ct * 16 + lr]),
                                             0.03125f * acc[rt][ct][j]);
                        if (dd <= thr) {
                            int s = atomicAdd(&cnt[grow * NC8 + c8], 1);
                            if (s < SLOTS) {
                                size_t base = ((size_t)grow * NC8 + c8) * SLOTS + s;
                                cand_i[base] = c16 * 64 + ct * 16 + lr;
                                cand_d[base] = dd;
                            }
                        }
                    }
                }
        }
        __syncthreads();   // seg+1 buffer staged & all reads of cur done
    }
}

// ---------------- rescore stage 1: filter + fastpath + two worklists --------
__global__ __launch_bounds__(256) void rescore_fast_kernel(
    const float* __restrict__ epsr, const float* __restrict__ cqmin,
    const int* __restrict__ cnt, const float* __restrict__ cand_d,
    const int* __restrict__ cand_i, int* __restrict__ out_idx,
    float* __restrict__ out_idx_f, int* __restrict__ wl, int* __restrict__ wl_cnt,
    int* __restrict__ wl2, int* __restrict__ wl2_cnt,
    int* __restrict__ np, int* __restrict__ pc) {
    const int row = blockIdx.x * 256 + threadIdx.x;
    const int lane = threadIdx.x & 63;
    float cq[NC16];
#pragma unroll
    for (int i = 0; i < 4; ++i)
        *(float4*)&cq[i * 4] = *(const float4*)(cqmin + (size_t)row * NC16 + i * 4);
    float gmin = __builtin_inff();
#pragma unroll
    for (int i = 0; i < NC16; ++i) gmin = fminf(gmin, cq[i]);
    const float thr = fmaf(2.0f, epsr[row], gmin);

    int nc = 0, first_c = 0;
    bool scan = false;
#pragma unroll
    for (int c8 = 0; c8 < NC8; ++c8) {
        if (fminf(cq[2 * c8], cq[2 * c8 + 1]) > thr) continue;
        int n = cnt[(size_t)row * NC8 + c8];
        if (n > SLOTS) { scan = true; }
        else {
            for (int s = 0; s < n; ++s) {
                size_t base = ((size_t)row * NC8 + c8) * SLOTS + s;
                if (cand_d[base] <= thr) {
                    int c = cand_i[base];
                    if (nc == 0) first_c = c;
                    if (nc < MAXP) pc[(size_t)row * MAXP + nc] = c;
                    ++nc;
                }
            }
        }
    }
    if (nc > MAXP) scan = true;
    const bool fast = !scan && nc == 1;
    const bool pair = !scan && nc != 1;
    if (fast) {
        out_idx[row] = first_c;
        out_idx_f[row] = (float)first_c;
    } else if (pair) {
        np[row] = nc;
    }
    {
        u64 mask = __ballot(pair);
        int cw = __popcll(mask);
        int base = 0;
        if (lane == 0 && cw) base = atomicAdd(wl_cnt, cw);
        base = __shfl(base, 0, 64);
        if (pair) {
            int rank = __popcll(mask & ((1ull << lane) - 1ull));
            wl[base + rank] = row;
        }
    }
    {
        u64 mask = __ballot(scan);
        int cw = __popcll(mask);
        int base = 0;
        if (lane == 0 && cw) base = atomicAdd(wl2_cnt, cw);
        base = __shfl(base, 0, 64);
        if (scan) {
            int rank = __popcll(mask & ((1ull << lane) - 1ull));
            wl2[base + rank] = row;
        }
    }
}

// ---------------- rescore stage 2a: thread-per-(pair-row, candidate) --------
__global__ __launch_bounds__(256) void rescore_pair_kernel(
    const float* __restrict__ z, const float* __restrict__ e,
    const float* __restrict__ sz, const float* __restrict__ se,
    const int* __restrict__ np, const int* __restrict__ pc,
    const int* __restrict__ wl, const int* __restrict__ wl_cnt,
    u64* __restrict__ rkey) {
    const int total = wl_cnt[0] * MAXP;
    for (int t = blockIdx.x * 256 + threadIdx.x; t < total; t += gridDim.x * 256) {
        const int wi = t >> 4, j = t & 15;
        const int row = wl[wi];
        if (j >= np[row]) continue;
        int c = pc[(size_t)row * MAXP + j];
        float m = exact_dot(z + (size_t)row * ZDIM, e + (size_t)c * ZDIM);
        float d = __fsub_rn(__fadd_rn(sz[row], se[c]), 2.0f * m);
        u64 key = ((u64)mono32(d) << 32) | (u32)c;
        atomicMin(&rkey[row], key);
    }
}

// ---------------- rescore stage 2b: thread-per-(scan-row, code) -------------
__global__ __launch_bounds__(256) void rescore_scan_kernel(
    const float* __restrict__ z, const float* __restrict__ e,
    const float* __restrict__ sz, const float* __restrict__ se,
    const float* __restrict__ epsr, const float* __restrict__ cqmin,
    const int* __restrict__ wl2, const int* __restrict__ wl2_cnt,
    u64* __restrict__ rkey) {
    const int total = wl2_cnt[0] * KCODES;
    for (int t = blockIdx.x * 256 + threadIdx.x; t < total; t += gridDim.x * 256) {
        const int si = t >> 10, c = t & 1023;
        const int row = wl2[si];
        float gmin = __builtin_inff();
#pragma unroll
        for (int i = 0; i < NC16; ++i)
            gmin = fminf(gmin, cqmin[(size_t)row * NC16 + i]);
        const float thr = fmaf(2.0f, epsr[row], gmin);
        const int c8 = c >> 7;
        if (fminf(cqmin[(size_t)row * NC16 + 2 * c8],
                  cqmin[(size_t)row * NC16 + 2 * c8 + 1]) > thr) continue;
        float m = exact_dot(z + (size_t)row * ZDIM, e + (size_t)c * ZDIM);
        float d = __fsub_rn(__fadd_rn(sz[row], se[c]), 2.0f * m);
        u64 key = ((u64)mono32(d) << 32) | (u32)c;
        atomicMin(&rkey[row], key);
    }
}

// ---------------- rescore stage 3: unpack winners (both lists) --------------
__global__ __launch_bounds__(256) void rescore_final_kernel(
    const int* __restrict__ wl, const int* __restrict__ wl_cnt,
    const int* __restrict__ wl2, const int* __restrict__ wl2_cnt,
    const u64* __restrict__ rkey, int* __restrict__ out_idx,
    float* __restrict__ out_idx_f) {
    const int i = blockIdx.x * 256 + threadIdx.x;
    const int n1 = wl_cnt[0], n2 = wl2_cnt[0];
    if (i < n1 + n2) {
        const int row = (i < n1) ? wl[i] : wl2[i - n1];
        const int c = (int)(u32)rkey[row];
        out_idx[row] = c;
        out_idx_f[row] = (float)c;
    }
}

// ---------------- z_q_st + loss partial (no atomics) ----------------
__global__ __launch_bounds__(256) void zq_loss_kernel(
    const float* __restrict__ z, const float* __restrict__ e,
    const int* __restrict__ idx, float* __restrict__ out,
    double* __restrict__ partial) {
    const int tid = threadIdx.x;
    const int rl  = tid >> 6;
    const int ln  = tid & 63;
    const int row0 = blockIdx.x * 32;

    float acc = 0.0f;
#pragma unroll
    for (int it = 0; it < 8; ++it) {
        int row = row0 + it * 4 + rl;
        int code = idx[row];
        const float4 vz = *(const float4*)(z + (size_t)row  * ZDIM + ln * 4);
        const float4 vq = *(const float4*)(e + (size_t)code * ZDIM + ln * 4);
        float4 o;
        float dx = __fsub_rn(vq.x, vz.x);
        float dy = __fsub_rn(vq.y, vz.y);
        float dz_ = __fsub_rn(vq.z, vz.z);
        float dw = __fsub_rn(vq.w, vz.w);
        o.x = __fadd_rn(vz.x, dx);
        o.y = __fadd_rn(vz.y, dy);
        o.z = __fadd_rn(vz.z, dz_);
        o.w = __fadd_rn(vz.w, dw);
        *(float4*)(out + (size_t)row * ZDIM + ln * 4) = o;
        acc = __fadd_rn(acc, __fmul_rn(dx, dx));
        acc = __fadd_rn(acc, __fmul_rn(dy, dy));
        acc = __fadd_rn(acc, __fmul_rn(dz_, dz_));
        acc = __fadd_rn(acc, __fmul_rn(dw, dw));
    }

    __shared__ double red[256];
    red[tid] = (double)acc;
    __syncthreads();
#pragma unroll
    for (int s = 128; s > 0; s >>= 1) {
        if (tid < s) red[tid] += red[tid + s];
        __syncthreads();
    }
    if (tid == 0) partial[blockIdx.x] = red[0];
}

__global__ __launch_bounds__(256) void loss_final_kernel(
    const double* __restrict__ partial, float* __restrict__ out_loss) {
    const int tid = threadIdx.x;
    double s = 0.0;
    for (int i = tid; i < ZQ_BLOCKS; i += 256) s += partial[i];
    __shared__ double red[256];
    red[tid] = s;
    __syncthreads();
#pragma unroll
    for (int st = 128; st > 0; st >>= 1) {
        if (tid < st) red[tid] += red[tid + st];
        __syncthreads();
    }
    if (tid == 0) {
        double M = red[0] / 16777216.0;
        float m32 = (float)M;
        out_loss[0] = __fadd_rn(m32, __fmul_rn(0.25f, m32));
    }
}

extern "C" void kernel_launch(void* const* d_in, const int* in_sizes, int n_in,
                              void* d_out, int out_size, void* d_ws, size_t ws_size,
                              hipStream_t stream) {
    const float* z = (const float*)d_in[0];
    const float* e = (const float*)d_in[1];
    float* out = (float*)d_out;
    char* ws = (char*)d_ws;

    size_t off = 0;
    double* partial = (double*)(ws + off); off += ZQ_BLOCKS * sizeof(double);        // 16 KB
    float*  sz      = (float*) (ws + off); off += (size_t)N_ROWS * 4;                // 256 KB
    float*  epsr    = (float*) (ws + off); off += (size_t)N_ROWS * 4;                // 256 KB
    float*  se      = (float*) (ws + off); off += (size_t)KCODES * 4;                // 4 KB
    int*    idx     = (int*)   (ws + off); off += (size_t)N_ROWS * 4;                // 256 KB
    u16*    ehf     = (u16*)   (ws + off); off += (size_t)KCODES * ZDIM * 2;         // 512 KB
    float*  cqmin   = (float*) (ws + off); off += (size_t)N_ROWS * NC16 * 4;         // 4 MB
    int*    cnt     = (int*)   (ws + off); off += (size_t)N_ROWS * NC8 * 4;          // 2 MB
    float*  cand_d  = (float*) (ws + off); off += (size_t)N_ROWS * NC8 * SLOTS * 4;  // 8 MB
    int*    cand_i  = (int*)   (ws + off); off += (size_t)N_ROWS * NC8 * SLOTS * 4;  // 8 MB
    int*    wl      = (int*)   (ws + off); off += (size_t)N_ROWS * 4;                // 256 KB
    int*    wl2     = (int*)   (ws + off); off += (size_t)N_ROWS * 4;                // 256 KB
    int*    np      = (int*)   (ws + off); off += (size_t)N_ROWS * 4;                // 256 KB
    int*    pc      = (int*)   (ws + off); off += (size_t)N_ROWS * MAXP * 4;         // 4 MB
    u64*    rkey    = (u64*)   (ws + off); off += (size_t)N_ROWS * 8;                // 512 KB
    int*    wl_cnt  = (int*)   (ws + off); off += 16;
    int*    wl2_cnt = (int*)   (ws + off); off += 16;

    u16* zh = (u16*)out;   // fp16 z in d_out z_q region; zq_loss overwrites later

    hipMemsetAsync(cnt, 0, (size_t)N_ROWS * NC8 * 4, stream);
    hipMemsetAsync(wl_cnt, 0, 32, stream);
    hipMemsetAsync(rkey, 0xFF, (size_t)N_ROWS * 8, stream);
    split_z_kernel<<<8192, 256, 0, stream>>>(z, zh);
    split_e_kernel<<<256, 256, 0, stream>>>(e, ehf);
    rowsq_eps_kernel<<<N_ROWS / 256, 256, 0, stream>>>(z, sz, epsr);
    rowsq_kernel<<<KCODES / 256, 256, 0, stream>>>(e, se, KCODES);
    mfma_argmin_kernel<<<1024, 256, 0, stream>>>(zh, ehf, sz, se, epsr, cqmin, cnt, cand_d, cand_i);
    rescore_fast_kernel<<<N_ROWS / 256, 256, 0, stream>>>(epsr, cqmin, cnt, cand_d, cand_i,
                                                          idx, out + IDX_OFF, wl, wl_cnt,
                                                          wl2, wl2_cnt, np, pc);
    rescore_pair_kernel<<<1024, 256, 0, stream>>>(z, e, sz, se, np, pc, wl, wl_cnt, rkey);
    rescore_scan_kernel<<<1024, 256, 0, stream>>>(z, e, sz, se, epsr, cqmin, wl2, wl2_cnt, rkey);
    rescore_final_kernel<<<N_ROWS / 256, 256, 0, stream>>>(wl, wl_cnt, wl2, wl2_cnt, rkey,
                                                           idx, out + IDX_OFF);
    zq_loss_kernel<<<ZQ_BLOCKS, 256, 0, stream>>>(z, e, idx, out, partial);
    loss_final_kernel<<<1, 256, 0, stream>>>(partial, out + LOSS_OFF);
}

// Round 20
// 362.101 us; speedup vs baseline: 1.2083x; 1.2083x over previous
//
#include <hip/hip_runtime.h>
#include <hip/hip_bf16.h>
#include <math.h>

#define N_ROWS 65536
#define ZDIM   256
#define KCODES 1024
#define IDX_OFF  (N_ROWS * ZDIM)        // 16777216
#define LOSS_OFF (IDX_OFF + N_ROWS)     // 16842752
#define ZQ_BLOCKS 2048
#define SLOTS 4
#define NC16 16                          // cqmin granularity: 16 chunks of 64
#define NC8  8                           // cand-list granularity: 8 chunks of 128
#define MAXP 16                          // max pairs per row before scan-mode

typedef unsigned int u32;
typedef unsigned short u16;
typedef unsigned long long u64;
typedef __attribute__((ext_vector_type(8))) _Float16 hfrag;  // 8 fp16 (4 VGPR)
typedef __attribute__((ext_vector_type(4))) float ffrag;     // 4 fp32 acc

__device__ __forceinline__ u16 f2h(float x) {
    union { _Float16 h; u16 u; } c; c.h = (_Float16)x; return c.u;   // RN
}

// monotone float->u32 map (total order preserved, incl. negatives)
__device__ __forceinline__ u32 mono32(float d) {
    u32 b = __float_as_uint(d);
    return (b & 0x80000000u) ? ~b : (b | 0x80000000u);
}

// ---------------- numpy-pairwise helpers (256 cols) ----------------
__device__ __forceinline__ float np_pw128_sq(const float* __restrict__ p) {
    float r[8];
#pragma unroll
    for (int j = 0; j < 8; ++j) r[j] = __fmul_rn(p[j], p[j]);
    for (int i = 8; i < 128; i += 8) {
#pragma unroll
        for (int j = 0; j < 8; ++j)
            r[j] = __fadd_rn(r[j], __fmul_rn(p[i + j], p[i + j]));
    }
    float a = __fadd_rn(__fadd_rn(r[0], r[1]), __fadd_rn(r[2], r[3]));
    float b = __fadd_rn(__fadd_rn(r[4], r[5]), __fadd_rn(r[6], r[7]));
    return __fadd_rn(a, b);
}

__device__ __forceinline__ float pw128_abs(const float* __restrict__ p) {
    float r[8];
#pragma unroll
    for (int j = 0; j < 8; ++j) r[j] = fabsf(p[j]);
    for (int i = 8; i < 128; i += 8) {
#pragma unroll
        for (int j = 0; j < 8; ++j) r[j] += fabsf(p[i + j]);
    }
    return ((r[0] + r[1]) + (r[2] + r[3])) + ((r[4] + r[5]) + (r[6] + r[7]));
}

// exact OpenBLAS-order dot, float4 loads (same fmaf sequence, 4x fewer loads)
__device__ __forceinline__ float exact_dot(const float* __restrict__ zr,
                                           const float* __restrict__ er) {
    float m = 0.0f;
#pragma unroll 4
    for (int k = 0; k < ZDIM; k += 4) {
        float4 a = *(const float4*)(zr + k);
        float4 b = *(const float4*)(er + k);
        m = fmaf(a.x, b.x, m);
        m = fmaf(a.y, b.y, m);
        m = fmaf(a.z, b.z, m);
        m = fmaf(a.w, b.w, m);
    }
    return m;
}

__global__ void rowsq_kernel(const float* __restrict__ x, float* __restrict__ s, int nrows) {
    int r = blockIdx.x * blockDim.x + threadIdx.x;
    if (r >= nrows) return;
    const float* p = x + (size_t)r * ZDIM;
    s[r] = __fadd_rn(np_pw128_sq(p), np_pw128_sq(p + 128));
}

// sz (np-exact) + per-row rigorous eps for the 1-pass fp16 bound
__global__ void rowsq_eps_kernel(const float* __restrict__ x, float* __restrict__ s,
                                 float* __restrict__ epsr) {
    int r = blockIdx.x * blockDim.x + threadIdx.x;
    const float* p = x + (size_t)r * ZDIM;
    s[r] = __fadd_rn(np_pw128_sq(p), np_pw128_sq(p + 128));
    float S1 = pw128_abs(p) + pw128_abs(p + 128);
    epsr[r] = fmaf(S1, 1.1e-6f, 6e-5f);
}

// ---------------- z -> fp16 (RN), row-major, into d_out z_q region ----------
__global__ __launch_bounds__(256) void split_z_kernel(
    const float* __restrict__ z, u16* __restrict__ zh) {
    int t = blockIdx.x * 256 + threadIdx.x;
    int i = t * 8;
    float4 a = *(const float4*)(z + i);
    float4 b = *(const float4*)(z + i + 4);
    uint4 w;
    w.x = ((u32)f2h(a.y) << 16) | f2h(a.x);
    w.y = ((u32)f2h(a.w) << 16) | f2h(a.z);
    w.z = ((u32)f2h(b.y) << 16) | f2h(b.x);
    w.w = ((u32)f2h(b.w) << 16) | f2h(b.z);
    *(uint4*)(zh + i) = w;
}

// ---------------- e -> fp16 scaled x64, FRAGMENT-MAJOR layout ----------------
__global__ __launch_bounds__(256) void split_e_kernel(
    const float* __restrict__ e, u16* __restrict__ ehf) {
    int t = blockIdx.x * 256 + threadIdx.x;      // 65536 threads
    int c = t >> 6, kq = t & 63;                 // dims kq*4 .. +3
    float4 v = *(const float4*)(e + (size_t)c * ZDIM + kq * 4);
    ushort4 h;
    h.x = f2h(v.x * 64.0f); h.y = f2h(v.y * 64.0f);
    h.z = f2h(v.z * 64.0f); h.w = f2h(v.w * 64.0f);
    int c16 = c >> 6, ct = (c >> 4) & 3, lr = c & 15;
    int kc = kq >> 3, lk = (kq >> 1) & 3;
    int lane = lk * 16 + lr;
    size_t base = ((size_t)((c16 * 8 + kc) * 4 + ct) * 64 + lane) * 8 + ((kq * 4) & 7);
    *(ushort4*)(ehf + base) = h;
}

// ---------------- LDS-shared 1-pass fp16 MFMA (reg-staged, static idx) ------
// v20 = v19 with rule-#20 fix: the half-segment dimension is explicitly
// unrolled so every A[rt][kc] index is COMPILE-TIME (r19's runtime h made A
// spill to scratch: 199MB writes). Buffer parity == h (seg = 2cc+h), so
// buffer indices are compile-time too. Bit-identical math to r17.
__global__ __launch_bounds__(256) void mfma_argmin_kernel(
    const u16* __restrict__ zh, const u16* __restrict__ ehf,
    const float* __restrict__ sz, const float* __restrict__ se,
    const float* __restrict__ epsr, float* __restrict__ cqmin,
    int* __restrict__ cnt, float* __restrict__ cand_d, int* __restrict__ cand_i) {
    __shared__ __align__(16) char ehL[2][16384];      // 32 KB (double buffer)
    __shared__ float sse[KCODES];                     // 4 KB
    const int tid = threadIdx.x;
    const int lane = tid & 63;
    const int lr = lane & 15, lk = lane >> 4;
    const int rp = blockIdx.x >> 1, cp = blockIdx.x & 1;
    const int wr0 = rp * 128 + (tid >> 6) * 32;

    *(float4*)(sse + tid * 4) = *(const float4*)(se + tid * 4);

    float szv[2][4], epsv[2][4];
#pragma unroll
    for (int rt = 0; rt < 2; ++rt)
#pragma unroll
        for (int j = 0; j < 4; ++j) {
            szv[rt][j]  = sz[wr0 + rt * 16 + lk * 4 + j];
            epsv[rt][j] = epsr[wr0 + rt * 16 + lk * 4 + j];
        }

    hfrag A[2][8];
#pragma unroll
    for (int rt = 0; rt < 2; ++rt)
#pragma unroll
        for (int kc = 0; kc < 8; ++kc)
            A[rt][kc] = *(const hfrag*)(zh + (size_t)(wr0 + rt * 16 + lr) * ZDIM + kc * 32 + lk * 8);

    const char* ehpb = (const char*)ehf + (size_t)cp * 8 * 32768;  // this cp half

    // prologue: stage segment 0 into buf0
    {
        const char* src = ehpb;
        uint4 s0 = *(const uint4*)(src + tid * 16);
        uint4 s1 = *(const uint4*)(src + 4096 + tid * 16);
        uint4 s2 = *(const uint4*)(src + 8192 + tid * 16);
        uint4 s3 = *(const uint4*)(src + 12288 + tid * 16);
        *(uint4*)(&ehL[0][tid * 16])         = s0;
        *(uint4*)(&ehL[0][4096 + tid * 16])  = s1;
        *(uint4*)(&ehL[0][8192 + tid * 16])  = s2;
        *(uint4*)(&ehL[0][12288 + tid * 16]) = s3;
    }
    __syncthreads();   // seg0 staged; also covers sse init

    ffrag acc[2][4];

#pragma unroll 1
    for (int cc = 0; cc < 8; ++cc) {
        const int c16 = cp * 8 + cc;
        const int c8  = c16 >> 1;

        // ===== phase h=0: compute seg 2cc (buf0, kc 0..3); stage seg 2cc+1 -> buf1
        {
#pragma unroll
            for (int rt = 0; rt < 2; ++rt)
#pragma unroll
                for (int ct = 0; ct < 4; ++ct) acc[rt][ct] = (ffrag)(0.0f);
            const char* src = ehpb + (size_t)(2 * cc + 1) * 16384;
            uint4 s0 = *(const uint4*)(src + tid * 16);
            uint4 s1 = *(const uint4*)(src + 4096 + tid * 16);
            uint4 s2 = *(const uint4*)(src + 8192 + tid * 16);
            uint4 s3 = *(const uint4*)(src + 12288 + tid * 16);
            const char* buf = ehL[0];
#pragma unroll
            for (int kcl = 0; kcl < 4; ++kcl) {
#pragma unroll
                for (int ct = 0; ct < 4; ++ct) {
                    hfrag bh = *(const hfrag*)(buf + (size_t)(kcl * 4 + ct) * 1024 + (size_t)lane * 16);
                    acc[0][ct] = __builtin_amdgcn_mfma_f32_16x16x32_f16(A[0][kcl], bh, acc[0][ct], 0, 0, 0);
                    acc[1][ct] = __builtin_amdgcn_mfma_f32_16x16x32_f16(A[1][kcl], bh, acc[1][ct], 0, 0, 0);
                }
            }
            char* dst = ehL[1];
            *(uint4*)(dst + tid * 16)         = s0;
            *(uint4*)(dst + 4096 + tid * 16)  = s1;
            *(uint4*)(dst + 8192 + tid * 16)  = s2;
            *(uint4*)(dst + 12288 + tid * 16) = s3;
            __syncthreads();
        }

        // ===== phase h=1: compute seg 2cc+1 (buf1, kc 4..7); stage seg 2cc+2 -> buf0
        {
            uint4 s0, s1, s2, s3;
            const bool more = (cc < 7);
            if (more) {
                const char* src = ehpb + (size_t)(2 * cc + 2) * 16384;
                s0 = *(const uint4*)(src + tid * 16);
                s1 = *(const uint4*)(src + 4096 + tid * 16);
                s2 = *(const uint4*)(src + 8192 + tid * 16);
                s3 = *(const uint4*)(src + 12288 + tid * 16);
            }
            const char* buf = ehL[1];
#pragma unroll
            for (int kcl = 0; kcl < 4; ++kcl) {
#pragma unroll
                for (int ct = 0; ct < 4; ++ct) {
                    hfrag bh = *(const hfrag*)(buf + (size_t)(kcl * 4 + ct) * 1024 + (size_t)lane * 16);
                    acc[0][ct] = __builtin_amdgcn_mfma_f32_16x16x32_f16(A[0][4 + kcl], bh, acc[0][ct], 0, 0, 0);
                    acc[1][ct] = __builtin_amdgcn_mfma_f32_16x16x32_f16(A[1][4 + kcl], bh, acc[1][ct], 0, 0, 0);
                }
            }
            if (more) {
                char* dst = ehL[0];
                *(uint4*)(dst + tid * 16)         = s0;
                *(uint4*)(dst + 4096 + tid * 16)  = s1;
                *(uint4*)(dst + 8192 + tid * 16)  = s2;
                *(uint4*)(dst + 12288 + tid * 16) = s3;
            }

            // ---- epilogue for c16: d~ = fl(fl(sz+se) - acc/32) ----
            float rmin[2][4];
#pragma unroll
            for (int rt = 0; rt < 2; ++rt)
#pragma unroll
                for (int j = 0; j < 4; ++j) rmin[rt][j] = __builtin_inff();
#pragma unroll
            for (int rt = 0; rt < 2; ++rt)
#pragma unroll
                for (int ct = 0; ct < 4; ++ct) {
                    float sec = sse[c16 * 64 + ct * 16 + lr];
#pragma unroll
                    for (int j = 0; j < 4; ++j) {
                        float dd = __fsub_rn(__fadd_rn(szv[rt][j], sec), 0.03125f * acc[rt][ct][j]);
                        rmin[rt][j] = fminf(rmin[rt][j], dd);
                    }
                }
#pragma unroll
            for (int m = 1; m < 16; m <<= 1)
#pragma unroll
                for (int rt = 0; rt < 2; ++rt)
#pragma unroll
                    for (int j = 0; j < 4; ++j)
                        rmin[rt][j] = fminf(rmin[rt][j], __shfl_xor(rmin[rt][j], m, 64));
            if (lr == 0) {
#pragma unroll
                for (int rt = 0; rt < 2; ++rt)
#pragma unroll
                    for (int j = 0; j < 4; ++j)
                        cqmin[(size_t)(wr0 + rt * 16 + lk * 4 + j) * NC16 + c16] = rmin[rt][j];
            }
#pragma unroll
            for (int rt = 0; rt < 2; ++rt)
#pragma unroll
                for (int j = 0; j < 4; ++j) {
                    const float thr = fmaf(2.0f, epsv[rt][j], rmin[rt][j]);
                    const int grow = wr0 + rt * 16 + lk * 4 + j;
#pragma unroll
                    for (int ct = 0; ct < 4; ++ct) {
                        float dd = __fsub_rn(__fadd_rn(szv[rt][j], sse[c16 * 64 + ct * 16 + lr]),
                                             0.03125f * acc[rt][ct][j]);
                        if (dd <= thr) {
                            int s = atomicAdd(&cnt[grow * NC8 + c8], 1);
                            if (s < SLOTS) {
                                size_t base = ((size_t)grow * NC8 + c8) * SLOTS + s;
                                cand_i[base] = c16 * 64 + ct * 16 + lr;
                                cand_d[base] = dd;
                            }
                        }
                    }
                }
            __syncthreads();
        }
    }
}

// ---------------- rescore stage 1: filter + fastpath + two worklists --------
__global__ __launch_bounds__(256) void rescore_fast_kernel(
    const float* __restrict__ epsr, const float* __restrict__ cqmin,
    const int* __restrict__ cnt, const float* __restrict__ cand_d,
    const int* __restrict__ cand_i, int* __restrict__ out_idx,
    float* __restrict__ out_idx_f, int* __restrict__ wl, int* __restrict__ wl_cnt,
    int* __restrict__ wl2, int* __restrict__ wl2_cnt,
    int* __restrict__ np, int* __restrict__ pc) {
    const int row = blockIdx.x * 256 + threadIdx.x;
    const int lane = threadIdx.x & 63;
    float cq[NC16];
#pragma unroll
    for (int i = 0; i < 4; ++i)
        *(float4*)&cq[i * 4] = *(const float4*)(cqmin + (size_t)row * NC16 + i * 4);
    float gmin = __builtin_inff();
#pragma unroll
    for (int i = 0; i < NC16; ++i) gmin = fminf(gmin, cq[i]);
    const float thr = fmaf(2.0f, epsr[row], gmin);

    int nc = 0, first_c = 0;
    bool scan = false;
#pragma unroll
    for (int c8 = 0; c8 < NC8; ++c8) {
        if (fminf(cq[2 * c8], cq[2 * c8 + 1]) > thr) continue;
        int n = cnt[(size_t)row * NC8 + c8];
        if (n > SLOTS) { scan = true; }
        else {
            for (int s = 0; s < n; ++s) {
                size_t base = ((size_t)row * NC8 + c8) * SLOTS + s;
                if (cand_d[base] <= thr) {
                    int c = cand_i[base];
                    if (nc == 0) first_c = c;
                    if (nc < MAXP) pc[(size_t)row * MAXP + nc] = c;
                    ++nc;
                }
            }
        }
    }
    if (nc > MAXP) scan = true;
    const bool fast = !scan && nc == 1;
    const bool pair = !scan && nc != 1;
    if (fast) {
        out_idx[row] = first_c;
        out_idx_f[row] = (float)first_c;
    } else if (pair) {
        np[row] = nc;
    }
    {
        u64 mask = __ballot(pair);
        int cw = __popcll(mask);
        int base = 0;
        if (lane == 0 && cw) base = atomicAdd(wl_cnt, cw);
        base = __shfl(base, 0, 64);
        if (pair) {
            int rank = __popcll(mask & ((1ull << lane) - 1ull));
            wl[base + rank] = row;
        }
    }
    {
        u64 mask = __ballot(scan);
        int cw = __popcll(mask);
        int base = 0;
        if (lane == 0 && cw) base = atomicAdd(wl2_cnt, cw);
        base = __shfl(base, 0, 64);
        if (scan) {
            int rank = __popcll(mask & ((1ull << lane) - 1ull));
            wl2[base + rank] = row;
        }
    }
}

// ---------------- rescore stage 2a: thread-per-(pair-row, candidate) --------
__global__ __launch_bounds__(256) void rescore_pair_kernel(
    const float* __restrict__ z, const float* __restrict__ e,
    const float* __restrict__ sz, const float* __restrict__ se,
    const int* __restrict__ np, const int* __restrict__ pc,
    const int* __restrict__ wl, const int* __restrict__ wl_cnt,
    u64* __restrict__ rkey) {
    const int total = wl_cnt[0] * MAXP;
    for (int t = blockIdx.x * 256 + threadIdx.x; t < total; t += gridDim.x * 256) {
        const int wi = t >> 4, j = t & 15;
        const int row = wl[wi];
        if (j >= np[row]) continue;
        int c = pc[(size_t)row * MAXP + j];
        float m = exact_dot(z + (size_t)row * ZDIM, e + (size_t)c * ZDIM);
        float d = __fsub_rn(__fadd_rn(sz[row], se[c]), 2.0f * m);
        u64 key = ((u64)mono32(d) << 32) | (u32)c;
        atomicMin(&rkey[row], key);
    }
}

// ---------------- rescore stage 2b: thread-per-(scan-row, code) -------------
__global__ __launch_bounds__(256) void rescore_scan_kernel(
    const float* __restrict__ z, const float* __restrict__ e,
    const float* __restrict__ sz, const float* __restrict__ se,
    const float* __restrict__ epsr, const float* __restrict__ cqmin,
    const int* __restrict__ wl2, const int* __restrict__ wl2_cnt,
    u64* __restrict__ rkey) {
    const int total = wl2_cnt[0] * KCODES;
    for (int t = blockIdx.x * 256 + threadIdx.x; t < total; t += gridDim.x * 256) {
        const int si = t >> 10, c = t & 1023;
        const int row = wl2[si];
        float gmin = __builtin_inff();
#pragma unroll
        for (int i = 0; i < NC16; ++i)
            gmin = fminf(gmin, cqmin[(size_t)row * NC16 + i]);
        const float thr = fmaf(2.0f, epsr[row], gmin);
        const int c8 = c >> 7;
        if (fminf(cqmin[(size_t)row * NC16 + 2 * c8],
                  cqmin[(size_t)row * NC16 + 2 * c8 + 1]) > thr) continue;
        float m = exact_dot(z + (size_t)row * ZDIM, e + (size_t)c * ZDIM);
        float d = __fsub_rn(__fadd_rn(sz[row], se[c]), 2.0f * m);
        u64 key = ((u64)mono32(d) << 32) | (u32)c;
        atomicMin(&rkey[row], key);
    }
}

// ---------------- rescore stage 3: unpack winners (both lists) --------------
__global__ __launch_bounds__(256) void rescore_final_kernel(
    const int* __restrict__ wl, const int* __restrict__ wl_cnt,
    const int* __restrict__ wl2, const int* __restrict__ wl2_cnt,
    const u64* __restrict__ rkey, int* __restrict__ out_idx,
    float* __restrict__ out_idx_f) {
    const int i = blockIdx.x * 256 + threadIdx.x;
    const int n1 = wl_cnt[0], n2 = wl2_cnt[0];
    if (i < n1 + n2) {
        const int row = (i < n1) ? wl[i] : wl2[i - n1];
        const int c = (int)(u32)rkey[row];
        out_idx[row] = c;
        out_idx_f[row] = (float)c;
    }
}

// ---------------- z_q_st + loss partial (no atomics) ----------------
__global__ __launch_bounds__(256) void zq_loss_kernel(
    const float* __restrict__ z, const float* __restrict__ e,
    const int* __restrict__ idx, float* __restrict__ out,
    double* __restrict__ partial) {
    const int tid = threadIdx.x;
    const int rl  = tid >> 6;
    const int ln  = tid & 63;
    const int row0 = blockIdx.x * 32;

    float acc = 0.0f;
#pragma unroll
    for (int it = 0; it < 8; ++it) {
        int row = row0 + it * 4 + rl;
        int code = idx[row];
        const float4 vz = *(const float4*)(z + (size_t)row  * ZDIM + ln * 4);
        const float4 vq = *(const float4*)(e + (size_t)code * ZDIM + ln * 4);
        float4 o;
        float dx = __fsub_rn(vq.x, vz.x);
        float dy = __fsub_rn(vq.y, vz.y);
        float dz_ = __fsub_rn(vq.z, vz.z);
        float dw = __fsub_rn(vq.w, vz.w);
        o.x = __fadd_rn(vz.x, dx);
        o.y = __fadd_rn(vz.y, dy);
        o.z = __fadd_rn(vz.z, dz_);
        o.w = __fadd_rn(vz.w, dw);
        *(float4*)(out + (size_t)row * ZDIM + ln * 4) = o;
        acc = __fadd_rn(acc, __fmul_rn(dx, dx));
        acc = __fadd_rn(acc, __fmul_rn(dy, dy));
        acc = __fadd_rn(acc, __fmul_rn(dz_, dz_));
        acc = __fadd_rn(acc, __fmul_rn(dw, dw));
    }

    __shared__ double red[256];
    red[tid] = (double)acc;
    __syncthreads();
#pragma unroll
    for (int s = 128; s > 0; s >>= 1) {
        if (tid < s) red[tid] += red[tid + s];
        __syncthreads();
    }
    if (tid == 0) partial[blockIdx.x] = red[0];
}

__global__ __launch_bounds__(256) void loss_final_kernel(
    const double* __restrict__ partial, float* __restrict__ out_loss) {
    const int tid = threadIdx.x;
    double s = 0.0;
    for (int i = tid; i < ZQ_BLOCKS; i += 256) s += partial[i];
    __shared__ double red[256];
    red[tid] = s;
    __syncthreads();
#pragma unroll
    for (int st = 128; st > 0; st >>= 1) {
        if (tid < st) red[tid] += red[tid + st];
        __syncthreads();
    }
    if (tid == 0) {
        double M = red[0] / 16777216.0;
        float m32 = (float)M;
        out_loss[0] = __fadd_rn(m32, __fmul_rn(0.25f, m32));
    }
}

extern "C" void kernel_launch(void* const* d_in, const int* in_sizes, int n_in,
                              void* d_out, int out_size, void* d_ws, size_t ws_size,
                              hipStream_t stream) {
    const float* z = (const float*)d_in[0];
    const float* e = (const float*)d_in[1];
    float* out = (float*)d_out;
    char* ws = (char*)d_ws;

    size_t off = 0;
    double* partial = (double*)(ws + off); off += ZQ_BLOCKS * sizeof(double);        // 16 KB
    float*  sz      = (float*) (ws + off); off += (size_t)N_ROWS * 4;                // 256 KB
    float*  epsr    = (float*) (ws + off); off += (size_t)N_ROWS * 4;                // 256 KB
    float*  se      = (float*) (ws + off); off += (size_t)KCODES * 4;                // 4 KB
    int*    idx     = (int*)   (ws + off); off += (size_t)N_ROWS * 4;                // 256 KB
    u16*    ehf     = (u16*)   (ws + off); off += (size_t)KCODES * ZDIM * 2;         // 512 KB
    float*  cqmin   = (float*) (ws + off); off += (size_t)N_ROWS * NC16 * 4;         // 4 MB
    int*    cnt     = (int*)   (ws + off); off += (size_t)N_ROWS * NC8 * 4;          // 2 MB
    float*  cand_d  = (float*) (ws + off); off += (size_t)N_ROWS * NC8 * SLOTS * 4;  // 8 MB
    int*    cand_i  = (int*)   (ws + off); off += (size_t)N_ROWS * NC8 * SLOTS * 4;  // 8 MB
    int*    wl      = (int*)   (ws + off); off += (size_t)N_ROWS * 4;                // 256 KB
    int*    wl2     = (int*)   (ws + off); off += (size_t)N_ROWS * 4;                // 256 KB
    int*    np      = (int*)   (ws + off); off += (size_t)N_ROWS * 4;                // 256 KB
    int*    pc      = (int*)   (ws + off); off += (size_t)N_ROWS * MAXP * 4;         // 4 MB
    u64*    rkey    = (u64*)   (ws + off); off += (size_t)N_ROWS * 8;                // 512 KB
    int*    wl_cnt  = (int*)   (ws + off); off += 16;
    int*    wl2_cnt = (int*)   (ws + off); off += 16;

    u16* zh = (u16*)out;   // fp16 z in d_out z_q region; zq_loss overwrites later

    hipMemsetAsync(cnt, 0, (size_t)N_ROWS * NC8 * 4, stream);
    hipMemsetAsync(wl_cnt, 0, 32, stream);
    hipMemsetAsync(rkey, 0xFF, (size_t)N_ROWS * 8, stream);
    split_z_kernel<<<8192, 256, 0, stream>>>(z, zh);
    split_e_kernel<<<256, 256, 0, stream>>>(e, ehf);
    rowsq_eps_kernel<<<N_ROWS / 256, 256, 0, stream>>>(z, sz, epsr);
    rowsq_kernel<<<KCODES / 256, 256, 0, stream>>>(e, se, KCODES);
    mfma_argmin_kernel<<<1024, 256, 0, stream>>>(zh, ehf, sz, se, epsr, cqmin, cnt, cand_d, cand_i);
    rescore_fast_kernel<<<N_ROWS / 256, 256, 0, stream>>>(epsr, cqmin, cnt, cand_d, cand_i,
                                                          idx, out + IDX_OFF, wl, wl_cnt,
                                                          wl2, wl2_cnt, np, pc);
    rescore_pair_kernel<<<1024, 256, 0, stream>>>(z, e, sz, se, np, pc, wl, wl_cnt, rkey);
    rescore_scan_kernel<<<1024, 256, 0, stream>>>(z, e, sz, se, epsr, cqmin, wl2, wl2_cnt, rkey);
    rescore_final_kernel<<<N_ROWS / 256, 256, 0, stream>>>(wl, wl_cnt, wl2, wl2_cnt, rkey,
                                                           idx, out + IDX_OFF);
    zq_loss_kernel<<<ZQ_BLOCKS, 256, 0, stream>>>(z, e, idx, out, partial);
    loss_final_kernel<<<1, 256, 0, stream>>>(partial, out + LOSS_OFF);
}

// Round 21
// 239.952 us; speedup vs baseline: 1.8234x; 1.5091x over previous
//
#include <hip/hip_runtime.h>
#include <hip/hip_bf16.h>
#include <math.h>

#define N_ROWS 65536
#define ZDIM   256
#define KCODES 1024
#define IDX_OFF  (N_ROWS * ZDIM)        // 16777216
#define LOSS_OFF (IDX_OFF + N_ROWS)     // 16842752
#define ZQ_BLOCKS 2048
#define SLOTS 4
#define NC16 16                          // cqmin granularity: 16 chunks of 64
#define NC8  8                           // cand-list granularity: 8 chunks of 128
#define MAXP 16                          // max pairs per row before scan-mode

typedef unsigned int u32;
typedef unsigned short u16;
typedef unsigned long long u64;
typedef __attribute__((ext_vector_type(8))) _Float16 hfrag;  // 8 fp16 (4 VGPR)
typedef __attribute__((ext_vector_type(4))) float ffrag;     // 4 fp32 acc

__device__ __forceinline__ u16 f2h(float x) {
    union { _Float16 h; u16 u; } c; c.h = (_Float16)x; return c.u;   // RN
}

// monotone float->u32 map (total order preserved, incl. negatives)
__device__ __forceinline__ u32 mono32(float d) {
    u32 b = __float_as_uint(d);
    return (b & 0x80000000u) ? ~b : (b | 0x80000000u);
}

// ---------------- numpy-pairwise helpers (256 cols) ----------------
__device__ __forceinline__ float np_pw128_sq(const float* __restrict__ p) {
    float r[8];
#pragma unroll
    for (int j = 0; j < 8; ++j) r[j] = __fmul_rn(p[j], p[j]);
    for (int i = 8; i < 128; i += 8) {
#pragma unroll
        for (int j = 0; j < 8; ++j)
            r[j] = __fadd_rn(r[j], __fmul_rn(p[i + j], p[i + j]));
    }
    float a = __fadd_rn(__fadd_rn(r[0], r[1]), __fadd_rn(r[2], r[3]));
    float b = __fadd_rn(__fadd_rn(r[4], r[5]), __fadd_rn(r[6], r[7]));
    return __fadd_rn(a, b);
}

__device__ __forceinline__ float pw128_abs(const float* __restrict__ p) {
    float r[8];
#pragma unroll
    for (int j = 0; j < 8; ++j) r[j] = fabsf(p[j]);
    for (int i = 8; i < 128; i += 8) {
#pragma unroll
        for (int j = 0; j < 8; ++j) r[j] += fabsf(p[i + j]);
    }
    return ((r[0] + r[1]) + (r[2] + r[3])) + ((r[4] + r[5]) + (r[6] + r[7]));
}

// exact OpenBLAS-order dot, float4 loads (same fmaf sequence, 4x fewer loads)
__device__ __forceinline__ float exact_dot(const float* __restrict__ zr,
                                           const float* __restrict__ er) {
    float m = 0.0f;
#pragma unroll 4
    for (int k = 0; k < ZDIM; k += 4) {
        float4 a = *(const float4*)(zr + k);
        float4 b = *(const float4*)(er + k);
        m = fmaf(a.x, b.x, m);
        m = fmaf(a.y, b.y, m);
        m = fmaf(a.z, b.z, m);
        m = fmaf(a.w, b.w, m);
    }
    return m;
}

__global__ void rowsq_kernel(const float* __restrict__ x, float* __restrict__ s, int nrows) {
    int r = blockIdx.x * blockDim.x + threadIdx.x;
    if (r >= nrows) return;
    const float* p = x + (size_t)r * ZDIM;
    s[r] = __fadd_rn(np_pw128_sq(p), np_pw128_sq(p + 128));
}

// sz (np-exact) + per-row rigorous eps for the 1-pass fp16 bound
__global__ void rowsq_eps_kernel(const float* __restrict__ x, float* __restrict__ s,
                                 float* __restrict__ epsr) {
    int r = blockIdx.x * blockDim.x + threadIdx.x;
    const float* p = x + (size_t)r * ZDIM;
    s[r] = __fadd_rn(np_pw128_sq(p), np_pw128_sq(p + 128));
    float S1 = pw128_abs(p) + pw128_abs(p + 128);
    epsr[r] = fmaf(S1, 1.1e-6f, 6e-5f);
}

// ---------------- z -> fp16 (RN), row-major, into d_out z_q region ----------
__global__ __launch_bounds__(256) void split_z_kernel(
    const float* __restrict__ z, u16* __restrict__ zh) {
    int t = blockIdx.x * 256 + threadIdx.x;
    int i = t * 8;
    float4 a = *(const float4*)(z + i);
    float4 b = *(const float4*)(z + i + 4);
    uint4 w;
    w.x = ((u32)f2h(a.y) << 16) | f2h(a.x);
    w.y = ((u32)f2h(a.w) << 16) | f2h(a.z);
    w.z = ((u32)f2h(b.y) << 16) | f2h(b.x);
    w.w = ((u32)f2h(b.w) << 16) | f2h(b.z);
    *(uint4*)(zh + i) = w;
}

// ---------------- e -> fp16 scaled x64, FRAGMENT-MAJOR layout ----------------
__global__ __launch_bounds__(256) void split_e_kernel(
    const float* __restrict__ e, u16* __restrict__ ehf) {
    int t = blockIdx.x * 256 + threadIdx.x;      // 65536 threads
    int c = t >> 6, kq = t & 63;                 // dims kq*4 .. +3
    float4 v = *(const float4*)(e + (size_t)c * ZDIM + kq * 4);
    ushort4 h;
    h.x = f2h(v.x * 64.0f); h.y = f2h(v.y * 64.0f);
    h.z = f2h(v.z * 64.0f); h.w = f2h(v.w * 64.0f);
    int c16 = c >> 6, ct = (c >> 4) & 3, lr = c & 15;
    int kc = kq >> 3, lk = (kq >> 1) & 3;
    int lane = lk * 16 + lr;
    size_t base = ((size_t)((c16 * 8 + kc) * 4 + ct) * 64 + lane) * 8 + ((kq * 4) & 7);
    *(ushort4*)(ehf + base) = h;
}

// ---------------- LDS-shared 1-pass fp16 MFMA (ballot emission, NO atomics) --
// v21 = v20 with the emission path rebuilt: slot assignment via __ballot +
// popcount prefix within each row's 16-lane group (one ballot per (rt,j,ct)
// covers all 4 lk groups via 16-bit slices); per-row base carried across the
// c8 pair in static-indexed registers; cnt written directly by lane lr==0.
// Removes ~2M blocking device-scope atomicAdd round-trips (the suspected
// 147MB WRITE_SIZE + stall source). Deterministic ascending slot order.
__global__ __launch_bounds__(256) void mfma_argmin_kernel(
    const u16* __restrict__ zh, const u16* __restrict__ ehf,
    const float* __restrict__ sz, const float* __restrict__ se,
    const float* __restrict__ epsr, float* __restrict__ cqmin,
    int* __restrict__ cnt, float* __restrict__ cand_d, int* __restrict__ cand_i) {
    __shared__ __align__(16) char ehL[2][16384];      // 32 KB (double buffer)
    __shared__ float sse[KCODES];                     // 4 KB
    const int tid = threadIdx.x;
    const int lane = tid & 63;
    const int lr = lane & 15, lk = lane >> 4;
    const int rp = blockIdx.x >> 1, cp = blockIdx.x & 1;
    const int wr0 = rp * 128 + (tid >> 6) * 32;

    *(float4*)(sse + tid * 4) = *(const float4*)(se + tid * 4);

    float szv[2][4], epsv[2][4];
#pragma unroll
    for (int rt = 0; rt < 2; ++rt)
#pragma unroll
        for (int j = 0; j < 4; ++j) {
            szv[rt][j]  = sz[wr0 + rt * 16 + lk * 4 + j];
            epsv[rt][j] = epsr[wr0 + rt * 16 + lk * 4 + j];
        }

    hfrag A[2][8];
#pragma unroll
    for (int rt = 0; rt < 2; ++rt)
#pragma unroll
        for (int kc = 0; kc < 8; ++kc)
            A[rt][kc] = *(const hfrag*)(zh + (size_t)(wr0 + rt * 16 + lr) * ZDIM + kc * 32 + lk * 8);

    const char* ehpb = (const char*)ehf + (size_t)cp * 8 * 32768;  // this cp half

    // prologue: stage segment 0 into buf0
    {
        const char* src = ehpb;
        uint4 s0 = *(const uint4*)(src + tid * 16);
        uint4 s1 = *(const uint4*)(src + 4096 + tid * 16);
        uint4 s2 = *(const uint4*)(src + 8192 + tid * 16);
        uint4 s3 = *(const uint4*)(src + 12288 + tid * 16);
        *(uint4*)(&ehL[0][tid * 16])         = s0;
        *(uint4*)(&ehL[0][4096 + tid * 16])  = s1;
        *(uint4*)(&ehL[0][8192 + tid * 16])  = s2;
        *(uint4*)(&ehL[0][12288 + tid * 16]) = s3;
    }
    __syncthreads();   // seg0 staged; also covers sse init

    ffrag acc[2][4];
    int bcnt[2][4];    // per-row emission count, carried across each c8 pair

#pragma unroll 1
    for (int cc = 0; cc < 8; ++cc) {
        const int c16 = cp * 8 + cc;
        const int c8  = c16 >> 1;

        // ===== phase h=0: compute seg 2cc (buf0, kc 0..3); stage seg 2cc+1 -> buf1
        {
#pragma unroll
            for (int rt = 0; rt < 2; ++rt)
#pragma unroll
                for (int ct = 0; ct < 4; ++ct) acc[rt][ct] = (ffrag)(0.0f);
            const char* src = ehpb + (size_t)(2 * cc + 1) * 16384;
            uint4 s0 = *(const uint4*)(src + tid * 16);
            uint4 s1 = *(const uint4*)(src + 4096 + tid * 16);
            uint4 s2 = *(const uint4*)(src + 8192 + tid * 16);
            uint4 s3 = *(const uint4*)(src + 12288 + tid * 16);
            const char* buf = ehL[0];
#pragma unroll
            for (int kcl = 0; kcl < 4; ++kcl) {
#pragma unroll
                for (int ct = 0; ct < 4; ++ct) {
                    hfrag bh = *(const hfrag*)(buf + (size_t)(kcl * 4 + ct) * 1024 + (size_t)lane * 16);
                    acc[0][ct] = __builtin_amdgcn_mfma_f32_16x16x32_f16(A[0][kcl], bh, acc[0][ct], 0, 0, 0);
                    acc[1][ct] = __builtin_amdgcn_mfma_f32_16x16x32_f16(A[1][kcl], bh, acc[1][ct], 0, 0, 0);
                }
            }
            char* dst = ehL[1];
            *(uint4*)(dst + tid * 16)         = s0;
            *(uint4*)(dst + 4096 + tid * 16)  = s1;
            *(uint4*)(dst + 8192 + tid * 16)  = s2;
            *(uint4*)(dst + 12288 + tid * 16) = s3;
            __syncthreads();
        }

        // ===== phase h=1: compute seg 2cc+1 (buf1, kc 4..7); stage seg 2cc+2 -> buf0
        {
            uint4 s0, s1, s2, s3;
            const bool more = (cc < 7);
            if (more) {
                const char* src = ehpb + (size_t)(2 * cc + 2) * 16384;
                s0 = *(const uint4*)(src + tid * 16);
                s1 = *(const uint4*)(src + 4096 + tid * 16);
                s2 = *(const uint4*)(src + 8192 + tid * 16);
                s3 = *(const uint4*)(src + 12288 + tid * 16);
            }
            const char* buf = ehL[1];
#pragma unroll
            for (int kcl = 0; kcl < 4; ++kcl) {
#pragma unroll
                for (int ct = 0; ct < 4; ++ct) {
                    hfrag bh = *(const hfrag*)(buf + (size_t)(kcl * 4 + ct) * 1024 + (size_t)lane * 16);
                    acc[0][ct] = __builtin_amdgcn_mfma_f32_16x16x32_f16(A[0][4 + kcl], bh, acc[0][ct], 0, 0, 0);
                    acc[1][ct] = __builtin_amdgcn_mfma_f32_16x16x32_f16(A[1][4 + kcl], bh, acc[1][ct], 0, 0, 0);
                }
            }
            if (more) {
                char* dst = ehL[0];
                *(uint4*)(dst + tid * 16)         = s0;
                *(uint4*)(dst + 4096 + tid * 16)  = s1;
                *(uint4*)(dst + 8192 + tid * 16)  = s2;
                *(uint4*)(dst + 12288 + tid * 16) = s3;
            }

            // ---- epilogue for c16: d~ = fl(fl(sz+se) - acc/32) ----
            float rmin[2][4];
#pragma unroll
            for (int rt = 0; rt < 2; ++rt)
#pragma unroll
                for (int j = 0; j < 4; ++j) rmin[rt][j] = __builtin_inff();
#pragma unroll
            for (int rt = 0; rt < 2; ++rt)
#pragma unroll
                for (int ct = 0; ct < 4; ++ct) {
                    float sec = sse[c16 * 64 + ct * 16 + lr];
#pragma unroll
                    for (int j = 0; j < 4; ++j) {
                        float dd = __fsub_rn(__fadd_rn(szv[rt][j], sec), 0.03125f * acc[rt][ct][j]);
                        rmin[rt][j] = fminf(rmin[rt][j], dd);
                    }
                }
#pragma unroll
            for (int m = 1; m < 16; m <<= 1)
#pragma unroll
                for (int rt = 0; rt < 2; ++rt)
#pragma unroll
                    for (int j = 0; j < 4; ++j)
                        rmin[rt][j] = fminf(rmin[rt][j], __shfl_xor(rmin[rt][j], m, 64));
            if (lr == 0) {
#pragma unroll
                for (int rt = 0; rt < 2; ++rt)
#pragma unroll
                    for (int j = 0; j < 4; ++j)
                        cqmin[(size_t)(wr0 + rt * 16 + lk * 4 + j) * NC16 + c16] = rmin[rt][j];
            }
            // ---- ballot-based emission (no atomics) ----
            if ((cc & 1) == 0) {
#pragma unroll
                for (int rt = 0; rt < 2; ++rt)
#pragma unroll
                    for (int j = 0; j < 4; ++j) bcnt[rt][j] = 0;
            }
#pragma unroll
            for (int rt = 0; rt < 2; ++rt)
#pragma unroll
                for (int j = 0; j < 4; ++j) {
                    const float thr = fmaf(2.0f, epsv[rt][j], rmin[rt][j]);
                    const int grow = wr0 + rt * 16 + lk * 4 + j;
#pragma unroll
                    for (int ct = 0; ct < 4; ++ct) {
                        float dd = __fsub_rn(__fadd_rn(szv[rt][j], sse[c16 * 64 + ct * 16 + lr]),
                                             0.03125f * acc[rt][ct][j]);
                        const bool emit = (dd <= thr);
                        u64 bal = __ballot(emit);
                        u32 grp = (u32)(bal >> (lk * 16)) & 0xFFFFu;
                        if (emit) {
                            int slot = bcnt[rt][j] + __popc(grp & ((1u << lr) - 1u));
                            if (slot < SLOTS) {
                                size_t base = ((size_t)grow * NC8 + c8) * SLOTS + slot;
                                cand_i[base] = c16 * 64 + ct * 16 + lr;
                                cand_d[base] = dd;
                            }
                        }
                        bcnt[rt][j] += __popc(grp);
                    }
                }
            if (cc & 1) {
                if (lr == 0) {
#pragma unroll
                    for (int rt = 0; rt < 2; ++rt)
#pragma unroll
                        for (int j = 0; j < 4; ++j)
                            cnt[(size_t)(wr0 + rt * 16 + lk * 4 + j) * NC8 + c8] = bcnt[rt][j];
                }
            }
            __syncthreads();
        }
    }
}

// ---------------- rescore stage 1: filter + fastpath + two worklists --------
__global__ __launch_bounds__(256) void rescore_fast_kernel(
    const float* __restrict__ epsr, const float* __restrict__ cqmin,
    const int* __restrict__ cnt, const float* __restrict__ cand_d,
    const int* __restrict__ cand_i, int* __restrict__ out_idx,
    float* __restrict__ out_idx_f, int* __restrict__ wl, int* __restrict__ wl_cnt,
    int* __restrict__ wl2, int* __restrict__ wl2_cnt,
    int* __restrict__ np, int* __restrict__ pc) {
    const int row = blockIdx.x * 256 + threadIdx.x;
    const int lane = threadIdx.x & 63;
    float cq[NC16];
#pragma unroll
    for (int i = 0; i < 4; ++i)
        *(float4*)&cq[i * 4] = *(const float4*)(cqmin + (size_t)row * NC16 + i * 4);
    float gmin = __builtin_inff();
#pragma unroll
    for (int i = 0; i < NC16; ++i) gmin = fminf(gmin, cq[i]);
    const float thr = fmaf(2.0f, epsr[row], gmin);

    int nc = 0, first_c = 0;
    bool scan = false;
#pragma unroll
    for (int c8 = 0; c8 < NC8; ++c8) {
        if (fminf(cq[2 * c8], cq[2 * c8 + 1]) > thr) continue;
        int n = cnt[(size_t)row * NC8 + c8];
        if (n > SLOTS) { scan = true; }
        else {
            for (int s = 0; s < n; ++s) {
                size_t base = ((size_t)row * NC8 + c8) * SLOTS + s;
                if (cand_d[base] <= thr) {
                    int c = cand_i[base];
                    if (nc == 0) first_c = c;
                    if (nc < MAXP) pc[(size_t)row * MAXP + nc] = c;
                    ++nc;
                }
            }
        }
    }
    if (nc > MAXP) scan = true;
    const bool fast = !scan && nc == 1;
    const bool pair = !scan && nc != 1;
    if (fast) {
        out_idx[row] = first_c;
        out_idx_f[row] = (float)first_c;
    } else if (pair) {
        np[row] = nc;
    }
    {
        u64 mask = __ballot(pair);
        int cw = __popcll(mask);
        int base = 0;
        if (lane == 0 && cw) base = atomicAdd(wl_cnt, cw);
        base = __shfl(base, 0, 64);
        if (pair) {
            int rank = __popcll(mask & ((1ull << lane) - 1ull));
            wl[base + rank] = row;
        }
    }
    {
        u64 mask = __ballot(scan);
        int cw = __popcll(mask);
        int base = 0;
        if (lane == 0 && cw) base = atomicAdd(wl2_cnt, cw);
        base = __shfl(base, 0, 64);
        if (scan) {
            int rank = __popcll(mask & ((1ull << lane) - 1ull));
            wl2[base + rank] = row;
        }
    }
}

// ---------------- rescore stage 2a: thread-per-(pair-row, candidate) --------
__global__ __launch_bounds__(256) void rescore_pair_kernel(
    const float* __restrict__ z, const float* __restrict__ e,
    const float* __restrict__ sz, const float* __restrict__ se,
    const int* __restrict__ np, const int* __restrict__ pc,
    const int* __restrict__ wl, const int* __restrict__ wl_cnt,
    u64* __restrict__ rkey) {
    const int total = wl_cnt[0] * MAXP;
    for (int t = blockIdx.x * 256 + threadIdx.x; t < total; t += gridDim.x * 256) {
        const int wi = t >> 4, j = t & 15;
        const int row = wl[wi];
        if (j >= np[row]) continue;
        int c = pc[(size_t)row * MAXP + j];
        float m = exact_dot(z + (size_t)row * ZDIM, e + (size_t)c * ZDIM);
        float d = __fsub_rn(__fadd_rn(sz[row], se[c]), 2.0f * m);
        u64 key = ((u64)mono32(d) << 32) | (u32)c;
        atomicMin(&rkey[row], key);
    }
}

// ---------------- rescore stage 2b: thread-per-(scan-row, code) -------------
__global__ __launch_bounds__(256) void rescore_scan_kernel(
    const float* __restrict__ z, const float* __restrict__ e,
    const float* __restrict__ sz, const float* __restrict__ se,
    const float* __restrict__ epsr, const float* __restrict__ cqmin,
    const int* __restrict__ wl2, const int* __restrict__ wl2_cnt,
    u64* __restrict__ rkey) {
    const int total = wl2_cnt[0] * KCODES;
    for (int t = blockIdx.x * 256 + threadIdx.x; t < total; t += gridDim.x * 256) {
        const int si = t >> 10, c = t & 1023;
        const int row = wl2[si];
        float gmin = __builtin_inff();
#pragma unroll
        for (int i = 0; i < NC16; ++i)
            gmin = fminf(gmin, cqmin[(size_t)row * NC16 + i]);
        const float thr = fmaf(2.0f, epsr[row], gmin);
        const int c8 = c >> 7;
        if (fminf(cqmin[(size_t)row * NC16 + 2 * c8],
                  cqmin[(size_t)row * NC16 + 2 * c8 + 1]) > thr) continue;
        float m = exact_dot(z + (size_t)row * ZDIM, e + (size_t)c * ZDIM);
        float d = __fsub_rn(__fadd_rn(sz[row], se[c]), 2.0f * m);
        u64 key = ((u64)mono32(d) << 32) | (u32)c;
        atomicMin(&rkey[row], key);
    }
}

// ---------------- rescore stage 3: unpack winners (both lists) --------------
__global__ __launch_bounds__(256) void rescore_final_kernel(
    const int* __restrict__ wl, const int* __restrict__ wl_cnt,
    const int* __restrict__ wl2, const int* __restrict__ wl2_cnt,
    const u64* __restrict__ rkey, int* __restrict__ out_idx,
    float* __restrict__ out_idx_f) {
    const int i = blockIdx.x * 256 + threadIdx.x;
    const int n1 = wl_cnt[0], n2 = wl2_cnt[0];
    if (i < n1 + n2) {
        const int row = (i < n1) ? wl[i] : wl2[i - n1];
        const int c = (int)(u32)rkey[row];
        out_idx[row] = c;
        out_idx_f[row] = (float)c;
    }
}

// ---------------- z_q_st + loss partial (no atomics) ----------------
__global__ __launch_bounds__(256) void zq_loss_kernel(
    const float* __restrict__ z, const float* __restrict__ e,
    const int* __restrict__ idx, float* __restrict__ out,
    double* __restrict__ partial) {
    const int tid = threadIdx.x;
    const int rl  = tid >> 6;
    const int ln  = tid & 63;
    const int row0 = blockIdx.x * 32;

    float acc = 0.0f;
#pragma unroll
    for (int it = 0; it < 8; ++it) {
        int row = row0 + it * 4 + rl;
        int code = idx[row];
        const float4 vz = *(const float4*)(z + (size_t)row  * ZDIM + ln * 4);
        const float4 vq = *(const float4*)(e + (size_t)code * ZDIM + ln * 4);
        float4 o;
        float dx = __fsub_rn(vq.x, vz.x);
        float dy = __fsub_rn(vq.y, vz.y);
        float dz_ = __fsub_rn(vq.z, vz.z);
        float dw = __fsub_rn(vq.w, vz.w);
        o.x = __fadd_rn(vz.x, dx);
        o.y = __fadd_rn(vz.y, dy);
        o.z = __fadd_rn(vz.z, dz_);
        o.w = __fadd_rn(vz.w, dw);
        *(float4*)(out + (size_t)row * ZDIM + ln * 4) = o;
        acc = __fadd_rn(acc, __fmul_rn(dx, dx));
        acc = __fadd_rn(acc, __fmul_rn(dy, dy));
        acc = __fadd_rn(acc, __fmul_rn(dz_, dz_));
        acc = __fadd_rn(acc, __fmul_rn(dw, dw));
    }

    __shared__ double red[256];
    red[tid] = (double)acc;
    __syncthreads();
#pragma unroll
    for (int s = 128; s > 0; s >>= 1) {
        if (tid < s) red[tid] += red[tid + s];
        __syncthreads();
    }
    if (tid == 0) partial[blockIdx.x] = red[0];
}

__global__ __launch_bounds__(256) void loss_final_kernel(
    const double* __restrict__ partial, float* __restrict__ out_loss) {
    const int tid = threadIdx.x;
    double s = 0.0;
    for (int i = tid; i < ZQ_BLOCKS; i += 256) s += partial[i];
    __shared__ double red[256];
    red[tid] = s;
    __syncthreads();
#pragma unroll
    for (int st = 128; st > 0; st >>= 1) {
        if (tid < st) red[tid] += red[tid + st];
        __syncthreads();
    }
    if (tid == 0) {
        double M = red[0] / 16777216.0;
        float m32 = (float)M;
        out_loss[0] = __fadd_rn(m32, __fmul_rn(0.25f, m32));
    }
}

extern "C" void kernel_launch(void* const* d_in, const int* in_sizes, int n_in,
                              void* d_out, int out_size, void* d_ws, size_t ws_size,
                              hipStream_t stream) {
    const float* z = (const float*)d_in[0];
    const float* e = (const float*)d_in[1];
    float* out = (float*)d_out;
    char* ws = (char*)d_ws;

    size_t off = 0;
    double* partial = (double*)(ws + off); off += ZQ_BLOCKS * sizeof(double);        // 16 KB
    float*  sz      = (float*) (ws + off); off += (size_t)N_ROWS * 4;                // 256 KB
    float*  epsr    = (float*) (ws + off); off += (size_t)N_ROWS * 4;                // 256 KB
    float*  se      = (float*) (ws + off); off += (size_t)KCODES * 4;                // 4 KB
    int*    idx     = (int*)   (ws + off); off += (size_t)N_ROWS * 4;                // 256 KB
    u16*    ehf     = (u16*)   (ws + off); off += (size_t)KCODES * ZDIM * 2;         // 512 KB
    float*  cqmin   = (float*) (ws + off); off += (size_t)N_ROWS * NC16 * 4;         // 4 MB
    int*    cnt     = (int*)   (ws + off); off += (size_t)N_ROWS * NC8 * 4;          // 2 MB
    float*  cand_d  = (float*) (ws + off); off += (size_t)N_ROWS * NC8 * SLOTS * 4;  // 8 MB
    int*    cand_i  = (int*)   (ws + off); off += (size_t)N_ROWS * NC8 * SLOTS * 4;  // 8 MB
    int*    wl      = (int*)   (ws + off); off += (size_t)N_ROWS * 4;                // 256 KB
    int*    wl2     = (int*)   (ws + off); off += (size_t)N_ROWS * 4;                // 256 KB
    int*    np      = (int*)   (ws + off); off += (size_t)N_ROWS * 4;                // 256 KB
    int*    pc      = (int*)   (ws + off); off += (size_t)N_ROWS * MAXP * 4;         // 4 MB
    u64*    rkey    = (u64*)   (ws + off); off += (size_t)N_ROWS * 8;                // 512 KB
    int*    wl_cnt  = (int*)   (ws + off); off += 16;
    int*    wl2_cnt = (int*)   (ws + off); off += 16;

    u16* zh = (u16*)out;   // fp16 z in d_out z_q region; zq_loss overwrites later

    hipMemsetAsync(wl_cnt, 0, 32, stream);
    hipMemsetAsync(rkey, 0xFF, (size_t)N_ROWS * 8, stream);
    split_z_kernel<<<8192, 256, 0, stream>>>(z, zh);
    split_e_kernel<<<256, 256, 0, stream>>>(e, ehf);
    rowsq_eps_kernel<<<N_ROWS / 256, 256, 0, stream>>>(z, sz, epsr);
    rowsq_kernel<<<KCODES / 256, 256, 0, stream>>>(e, se, KCODES);
    mfma_argmin_kernel<<<1024, 256, 0, stream>>>(zh, ehf, sz, se, epsr, cqmin, cnt, cand_d, cand_i);
    rescore_fast_kernel<<<N_ROWS / 256, 256, 0, stream>>>(epsr, cqmin, cnt, cand_d, cand_i,
                                                          idx, out + IDX_OFF, wl, wl_cnt,
                                                          wl2, wl2_cnt, np, pc);
    rescore_pair_kernel<<<1024, 256, 0, stream>>>(z, e, sz, se, np, pc, wl, wl_cnt, rkey);
    rescore_scan_kernel<<<1024, 256, 0, stream>>>(z, e, sz, se, epsr, cqmin, wl2, wl2_cnt, rkey);
    rescore_final_kernel<<<N_ROWS / 256, 256, 0, stream>>>(wl, wl_cnt, wl2, wl2_cnt, rkey,
                                                           idx, out + IDX_OFF);
    zq_loss_kernel<<<ZQ_BLOCKS, 256, 0, stream>>>(z, e, idx, out, partial);
    loss_final_kernel<<<1, 256, 0, stream>>>(partial, out + LOSS_OFF);
}